// Round 1
// baseline (157.924 us; speedup 1.0000x reference)
//
#include <hip/hip_runtime.h>
#include <math.h>

// Capsule dynamic routing, fully fused, 2-BATCH BLOCKED: one block of 512
// threads per (c, batch-pair). B=256, C=10, N=1152, Din=8, U=16, 3 iters.
//
// vs previous round (130 µs):
//  * Each block computes TWO batches b0,b1 for one c: every W float4 load now
//    feeds 8 FMAs instead of 4, and block-level L2 W-traffic halves
//    (1.47 GB -> 0.74 GB) -- the kernel was latency-bound on L2 W fetches.
//  * Routing logits b live in REGISTERS (the 4 lanes owning an n reach an
//    identical value via butterfly shuffles) -> b_s LDS + its syncs deleted.
//  * x read directly from global (4-lane broadcast of the same float4, each
//    byte touched exactly once per block; hits L2) -> 36 KB x_s deleted.
//    LDS drops 42.5 KB -> ~1.2 KB; occupancy becomes VGPR-bound.
//  * Iteration 0 peeled: softmax(ones) == 1/1152 exactly -> no exp / le
//    reduction on the first pass.
//  * sched_barrier(0) removed: the compiler may now overlap group k+1's W
//    loads with group k's FMAs; __launch_bounds__(512,4) caps VGPR at 128
//    (2 blocks/CU = 16 waves) so the live set (18 uh float4 + 18 b scalars
//    + temps ~= 115) cannot balloon or spill.

#define BATCH 256
#define CAPS  10
#define NIN   1152
#define DIN   8
#define UDIM  16
#define TPB   512

__global__ __launch_bounds__(TPB, 4) void capsule_routing_kernel(
    const float* __restrict__ x,   // (B, N, Din)
    const float* __restrict__ W,   // (C, N, Din, U)
    float* __restrict__ out)       // (B, C, U)
{
    const int gblk = blockIdx.x;      // c-major for L2 W-locality
    const int c    = gblk >> 7;       // 0..9
    const int bp   = gblk & 127;      // 0..127  (batch pair)
    const int b0   = bp << 1;
    const int t    = threadIdx.x;     // 0..511
    const int ub   = (t & 3) << 2;    // u base: 0,4,8,12
    const int gg   = t >> 2;          // 0..127 (n residue)
    const int wave = t >> 6;          // 0..7

    __shared__ float redB[2][8];        // per-wave exp-sum partials, per batch
    __shared__ float ps[2][8][UDIM];    // per-wave partial s, per batch
    __shared__ float v_s[2][UDIM];      // squashed output, per batch

    const float* Wc = W + (size_t)c * (NIN * DIN * UDIM);
    const float* xA = x + (size_t)b0 * (NIN * DIN);
    const float* xB = xA + (NIN * DIN);

    // u_hat in 18 NAMED float4 registers (array form spilled in earlier rounds)
    float4 uA0,uA1,uA2,uA3,uA4,uA5,uA6,uA7,uA8;
    float4 uB0,uB1,uB2,uB3,uB4,uB5,uB6,uB7,uB8;
    // routing logits, register-resident (identical across the 4 owner lanes)
    float bA0,bA1,bA2,bA3,bA4,bA5,bA6,bA7,bA8;
    float bB0,bB1,bB2,bB3,bB4,bB5,bB6,bB7,bB8;

#define UHC(K, DA, DB) { \
    const int n_ = gg + 128 * (K); \
    const float4* wr_ = (const float4*)(Wc + n_ * (DIN * UDIM) + ub); \
    const float4 xa_ = ((const float4*)(xA + n_ * DIN))[0]; \
    const float4 xb_ = ((const float4*)(xA + n_ * DIN))[1]; \
    const float4 ya_ = ((const float4*)(xB + n_ * DIN))[0]; \
    const float4 yb_ = ((const float4*)(xB + n_ * DIN))[1]; \
    float4 w0_ = wr_[0], w1_ = wr_[4], w2_ = wr_[8], w3_ = wr_[12]; \
    float4 a_, d_; \
    a_.x = xa_.x*w0_.x + xa_.y*w1_.x + xa_.z*w2_.x + xa_.w*w3_.x; \
    a_.y = xa_.x*w0_.y + xa_.y*w1_.y + xa_.z*w2_.y + xa_.w*w3_.y; \
    a_.z = xa_.x*w0_.z + xa_.y*w1_.z + xa_.z*w2_.z + xa_.w*w3_.z; \
    a_.w = xa_.x*w0_.w + xa_.y*w1_.w + xa_.z*w2_.w + xa_.w*w3_.w; \
    d_.x = ya_.x*w0_.x + ya_.y*w1_.x + ya_.z*w2_.x + ya_.w*w3_.x; \
    d_.y = ya_.x*w0_.y + ya_.y*w1_.y + ya_.z*w2_.y + ya_.w*w3_.y; \
    d_.z = ya_.x*w0_.z + ya_.y*w1_.z + ya_.z*w2_.z + ya_.w*w3_.z; \
    d_.w = ya_.x*w0_.w + ya_.y*w1_.w + ya_.z*w2_.w + ya_.w*w3_.w; \
    w0_ = wr_[16]; w1_ = wr_[20]; w2_ = wr_[24]; w3_ = wr_[28]; \
    a_.x += xb_.x*w0_.x + xb_.y*w1_.x + xb_.z*w2_.x + xb_.w*w3_.x; \
    a_.y += xb_.x*w0_.y + xb_.y*w1_.y + xb_.z*w2_.y + xb_.w*w3_.y; \
    a_.z += xb_.x*w0_.z + xb_.y*w1_.z + xb_.z*w2_.z + xb_.w*w3_.z; \
    a_.w += xb_.x*w0_.w + xb_.y*w1_.w + xb_.z*w2_.w + xb_.w*w3_.w; \
    d_.x += yb_.x*w0_.x + yb_.y*w1_.x + yb_.z*w2_.x + yb_.w*w3_.x; \
    d_.y += yb_.x*w0_.y + yb_.y*w1_.y + yb_.z*w2_.y + yb_.w*w3_.y; \
    d_.z += yb_.x*w0_.z + yb_.y*w1_.z + yb_.z*w2_.z + yb_.w*w3_.z; \
    d_.w += yb_.x*w0_.w + yb_.y*w1_.w + yb_.z*w2_.w + yb_.w*w3_.w; \
    DA = a_; DB = d_; }

    UHC(0, uA0, uB0)
    UHC(1, uA1, uB1)
    UHC(2, uA2, uB2)
    UHC(3, uA3, uB3)
    UHC(4, uA4, uB4)
    UHC(5, uA5, uB5)
    UHC(6, uA6, uB6)
    UHC(7, uA7, uB7)
    UHC(8, uA8, uB8)

    float4 pA, pB;
    float leA, leB;

    // ---- reduction helpers ----
#define PSTAGE(MK) { \
    pA.x += __shfl_xor(pA.x, MK); pA.y += __shfl_xor(pA.y, MK); \
    pA.z += __shfl_xor(pA.z, MK); pA.w += __shfl_xor(pA.w, MK); \
    pB.x += __shfl_xor(pB.x, MK); pB.y += __shfl_xor(pB.y, MK); \
    pB.z += __shfl_xor(pB.z, MK); pB.w += __shfl_xor(pB.w, MK); }

#define PRED_WRITE() { \
    PSTAGE(4) PSTAGE(8) PSTAGE(16) PSTAGE(32) \
    if ((t & 63) < 4) { \
        ps[0][wave][ub+0] = pA.x; ps[0][wave][ub+1] = pA.y; \
        ps[0][wave][ub+2] = pA.z; ps[0][wave][ub+3] = pA.w; \
        ps[1][wave][ub+0] = pB.x; ps[1][wave][ub+1] = pB.y; \
        ps[1][wave][ub+2] = pB.z; ps[1][wave][ub+3] = pB.w; \
    } }

    // squash: threads 0..31 (wave 0). bi = batch, u = component.
#define SQUASH(USE_RED, WROUT) { \
    __syncthreads(); \
    if (t < 32) { \
        const int bi_ = t >> 4, u_ = t & 15; \
        float inv_; \
        if (USE_RED) { \
            float es_ = 0.f; \
            es_ += redB[bi_][0]; es_ += redB[bi_][1]; es_ += redB[bi_][2]; es_ += redB[bi_][3]; \
            es_ += redB[bi_][4]; es_ += redB[bi_][5]; es_ += redB[bi_][6]; es_ += redB[bi_][7]; \
            inv_ = 4.0f / es_;               /* 4x lane overcount in le */ \
        } else { \
            inv_ = 1.0f / 1152.0f;           /* softmax(ones) is uniform */ \
        } \
        float s_ = 0.f; \
        s_ += ps[bi_][0][u_]; s_ += ps[bi_][1][u_]; s_ += ps[bi_][2][u_]; s_ += ps[bi_][3][u_]; \
        s_ += ps[bi_][4][u_]; s_ += ps[bi_][5][u_]; s_ += ps[bi_][6][u_]; s_ += ps[bi_][7][u_]; \
        s_ *= inv_; \
        float sq_ = s_ * s_; \
        sq_ += __shfl_xor(sq_, 1); sq_ += __shfl_xor(sq_, 2); \
        sq_ += __shfl_xor(sq_, 4); sq_ += __shfl_xor(sq_, 8); \
        const float sc_ = sq_ / ((1.0f + sq_) * sqrtf(sq_ + 1e-9f)); \
        const float v_ = sc_ * s_; \
        v_s[bi_][u_] = v_; \
        if (WROUT) out[((size_t)(b0 + bi_) * CAPS + c) * UDIM + u_] = v_; \
    } \
    __syncthreads(); }

    // b update: butterfly over the 4 owner lanes -> all 4 agree exactly.
#define BUP(UA, UB, BA, BB, INIT) { \
    float qa_ = UA.x*vA_.x + UA.y*vA_.y + UA.z*vA_.z + UA.w*vA_.w; \
    float qb_ = UB.x*vB_.x + UB.y*vB_.y + UB.z*vB_.z + UB.w*vB_.w; \
    qa_ += __shfl_xor(qa_, 1); qa_ += __shfl_xor(qa_, 2); \
    qb_ += __shfl_xor(qb_, 1); qb_ += __shfl_xor(qb_, 2); \
    if (INIT) { BA = 1.0f + qa_; BB = 1.0f + qb_; } \
    else      { BA += qa_;       BB += qb_; } }

#define BUPD_ALL(INIT) { \
    const float4 vA_ = *(const float4*)(&v_s[0][ub]); \
    const float4 vB_ = *(const float4*)(&v_s[1][ub]); \
    BUP(uA0, uB0, bA0, bB0, INIT) BUP(uA1, uB1, bA1, bB1, INIT) \
    BUP(uA2, uB2, bA2, bB2, INIT) BUP(uA3, uB3, bA3, bB3, INIT) \
    BUP(uA4, uB4, bA4, bB4, INIT) BUP(uA5, uB5, bA5, bB5, INIT) \
    BUP(uA6, uB6, bA6, bB6, INIT) BUP(uA7, uB7, bA7, bB7, INIT) \
    BUP(uA8, uB8, bA8, bB8, INIT) }

#define PADD(UA, UB) { \
    pA.x += UA.x; pA.y += UA.y; pA.z += UA.z; pA.w += UA.w; \
    pB.x += UB.x; pB.y += UB.y; pB.z += UB.z; pB.w += UB.w; }

#define ACCE(UA, UB, BA, BB) { \
    const float eA_ = expf(BA); const float eB_ = expf(BB); \
    leA += eA_; leB += eB_; \
    pA.x += eA_*UA.x; pA.y += eA_*UA.y; pA.z += eA_*UA.z; pA.w += eA_*UA.w; \
    pB.x += eB_*UB.x; pB.y += eB_*UB.y; pB.z += eB_*UB.z; pB.w += eB_*UB.w; }

#define LERED_WRITE() { \
    leA += __shfl_xor(leA, 1);  leB += __shfl_xor(leB, 1); \
    leA += __shfl_xor(leA, 2);  leB += __shfl_xor(leB, 2); \
    leA += __shfl_xor(leA, 4);  leB += __shfl_xor(leB, 4); \
    leA += __shfl_xor(leA, 8);  leB += __shfl_xor(leB, 8); \
    leA += __shfl_xor(leA, 16); leB += __shfl_xor(leB, 16); \
    leA += __shfl_xor(leA, 32); leB += __shfl_xor(leB, 32); \
    if ((t & 63) == 0) { redB[0][wave] = leA; redB[1][wave] = leB; } }

    // ---- iteration 0: c is uniform 1/1152, no exp needed ----
    pA = uA0; pB = uB0;
    PADD(uA1, uB1) PADD(uA2, uB2) PADD(uA3, uB3) PADD(uA4, uB4)
    PADD(uA5, uB5) PADD(uA6, uB6) PADD(uA7, uB7) PADD(uA8, uB8)
    PRED_WRITE()
    SQUASH(0, 0)
    BUPD_ALL(1)            // b = 1 + u_hat . v0

    // ---- iteration 1 ----
    leA = 0.f; leB = 0.f;
    pA = make_float4(0.f, 0.f, 0.f, 0.f); pB = make_float4(0.f, 0.f, 0.f, 0.f);
    ACCE(uA0, uB0, bA0, bB0) ACCE(uA1, uB1, bA1, bB1) ACCE(uA2, uB2, bA2, bB2)
    ACCE(uA3, uB3, bA3, bB3) ACCE(uA4, uB4, bA4, bB4) ACCE(uA5, uB5, bA5, bB5)
    ACCE(uA6, uB6, bA6, bB6) ACCE(uA7, uB7, bA7, bB7) ACCE(uA8, uB8, bA8, bB8)
    LERED_WRITE()
    PRED_WRITE()
    SQUASH(1, 0)
    BUPD_ALL(0)            // b += u_hat . v1

    // ---- iteration 2 (writes out) ----
    leA = 0.f; leB = 0.f;
    pA = make_float4(0.f, 0.f, 0.f, 0.f); pB = make_float4(0.f, 0.f, 0.f, 0.f);
    ACCE(uA0, uB0, bA0, bB0) ACCE(uA1, uB1, bA1, bB1) ACCE(uA2, uB2, bA2, bB2)
    ACCE(uA3, uB3, bA3, bB3) ACCE(uA4, uB4, bA4, bB4) ACCE(uA5, uB5, bA5, bB5)
    ACCE(uA6, uB6, bA6, bB6) ACCE(uA7, uB7, bA7, bB7) ACCE(uA8, uB8, bA8, bB8)
    LERED_WRITE()
    PRED_WRITE()
    SQUASH(1, 1)
}

extern "C" void kernel_launch(void* const* d_in, const int* in_sizes, int n_in,
                              void* d_out, int out_size, void* d_ws, size_t ws_size,
                              hipStream_t stream) {
    const float* x = (const float*)d_in[0];   // (256, 1152, 8)
    const float* W = (const float*)d_in[1];   // (10, 1152, 8, 16)
    float* out = (float*)d_out;               // (256, 10, 16)
    capsule_routing_kernel<<<CAPS * (BATCH / 2), TPB, 0, stream>>>(x, W, out);
}

// Round 2
// 150.530 us; speedup vs baseline: 1.0491x; 1.0491x over previous
//
#include <hip/hip_runtime.h>
#include <math.h>

// Capsule dynamic routing, fully fused, 2-BATCH BLOCKED: one block of 512
// threads per (c, batch-pair). B=256, C=10, N=1152, Din=8, U=16, 3 iters.
//
// Round-2 fix of the round-1 spill disaster (VGPR pinned 64, 103 MB scratch
// writes): the 2-batch W-reuse is kept (halves L2 W traffic vs round 0), but
// the live set is brought back under the 128-VGPR cap of
// __launch_bounds__(512,4):
//  * routing logits b live in LDS (b_s[2][1152], 9.2 KB) -> -18 always-live
//    VGPRs. Each n's owner lanes and reader lanes are the same 4 consecutive
//    threads (same wave); the per-iteration __syncthreads() covers ordering.
//  * sched_barrier(0) after EVERY UHC group is REINSTATED (round-0 had it;
//    removing it let the scheduler overlap several groups' 8-load batches and
//    blew the register budget). Latency is hidden by TLP (16 waves/CU), not
//    per-wave ILP.
//  * u_hat stays in 18 NAMED float4 registers (array form spills).
//  * x read directly from global (4-lane broadcast, L2-resident) - no x_s.
//  * iteration 0 peeled: softmax(ones) == 1/1152 exactly.

#define BATCH 256
#define CAPS  10
#define NIN   1152
#define DIN   8
#define UDIM  16
#define TPB   512

__global__ __launch_bounds__(TPB, 4) void capsule_routing_kernel(
    const float* __restrict__ x,   // (B, N, Din)
    const float* __restrict__ W,   // (C, N, Din, U)
    float* __restrict__ out)       // (B, C, U)
{
    const int gblk = blockIdx.x;      // c-major for L2 W-locality
    const int c    = gblk >> 7;       // 0..9
    const int bp   = gblk & 127;      // 0..127  (batch pair)
    const int b0   = bp << 1;
    const int t    = threadIdx.x;     // 0..511
    const int ub   = (t & 3) << 2;    // u base: 0,4,8,12
    const int gg   = t >> 2;          // 0..127 (n residue)
    const int wave = t >> 6;          // 0..7

    __shared__ float b_s[2][NIN];       // routing logits, per batch (9.2 KB)
    __shared__ float redB[2][8];        // per-wave exp-sum partials, per batch
    __shared__ float ps[2][8][UDIM];    // per-wave partial s, per batch
    __shared__ float v_s[2][UDIM];      // squashed output, per batch

    const float* Wc = W + (size_t)c * (NIN * DIN * UDIM);
    const float* xA = x + (size_t)b0 * (NIN * DIN);
    const float* xB = xA + (NIN * DIN);

    // u_hat in 18 NAMED float4 registers (array form spilled in earlier rounds)
    float4 uA0,uA1,uA2,uA3,uA4,uA5,uA6,uA7,uA8;
    float4 uB0,uB1,uB2,uB3,uB4,uB5,uB6,uB7,uB8;

#define UHC(K, DA, DB) { \
    const int n_ = gg + 128 * (K); \
    const float4* wr_ = (const float4*)(Wc + n_ * (DIN * UDIM) + ub); \
    const float4 xa_ = ((const float4*)(xA + n_ * DIN))[0]; \
    const float4 xb_ = ((const float4*)(xA + n_ * DIN))[1]; \
    const float4 ya_ = ((const float4*)(xB + n_ * DIN))[0]; \
    const float4 yb_ = ((const float4*)(xB + n_ * DIN))[1]; \
    float4 w0_ = wr_[0], w1_ = wr_[4], w2_ = wr_[8], w3_ = wr_[12]; \
    float4 a_, d_; \
    a_.x = xa_.x*w0_.x + xa_.y*w1_.x + xa_.z*w2_.x + xa_.w*w3_.x; \
    a_.y = xa_.x*w0_.y + xa_.y*w1_.y + xa_.z*w2_.y + xa_.w*w3_.y; \
    a_.z = xa_.x*w0_.z + xa_.y*w1_.z + xa_.z*w2_.z + xa_.w*w3_.z; \
    a_.w = xa_.x*w0_.w + xa_.y*w1_.w + xa_.z*w2_.w + xa_.w*w3_.w; \
    d_.x = ya_.x*w0_.x + ya_.y*w1_.x + ya_.z*w2_.x + ya_.w*w3_.x; \
    d_.y = ya_.x*w0_.y + ya_.y*w1_.y + ya_.z*w2_.y + ya_.w*w3_.y; \
    d_.z = ya_.x*w0_.z + ya_.y*w1_.z + ya_.z*w2_.z + ya_.w*w3_.z; \
    d_.w = ya_.x*w0_.w + ya_.y*w1_.w + ya_.z*w2_.w + ya_.w*w3_.w; \
    w0_ = wr_[16]; w1_ = wr_[20]; w2_ = wr_[24]; w3_ = wr_[28]; \
    a_.x += xb_.x*w0_.x + xb_.y*w1_.x + xb_.z*w2_.x + xb_.w*w3_.x; \
    a_.y += xb_.x*w0_.y + xb_.y*w1_.y + xb_.z*w2_.y + xb_.w*w3_.y; \
    a_.z += xb_.x*w0_.z + xb_.y*w1_.z + xb_.z*w2_.z + xb_.w*w3_.z; \
    a_.w += xb_.x*w0_.w + xb_.y*w1_.w + xb_.z*w2_.w + xb_.w*w3_.w; \
    d_.x += yb_.x*w0_.x + yb_.y*w1_.x + yb_.z*w2_.x + yb_.w*w3_.x; \
    d_.y += yb_.x*w0_.y + yb_.y*w1_.y + yb_.z*w2_.y + yb_.w*w3_.y; \
    d_.z += yb_.x*w0_.z + yb_.y*w1_.z + yb_.z*w2_.z + yb_.w*w3_.z; \
    d_.w += yb_.x*w0_.w + yb_.y*w1_.w + yb_.z*w2_.w + yb_.w*w3_.w; \
    DA = a_; DB = d_; } \
    __builtin_amdgcn_sched_barrier(0);

    UHC(0, uA0, uB0)
    UHC(1, uA1, uB1)
    UHC(2, uA2, uB2)
    UHC(3, uA3, uB3)
    UHC(4, uA4, uB4)
    UHC(5, uA5, uB5)
    UHC(6, uA6, uB6)
    UHC(7, uA7, uB7)
    UHC(8, uA8, uB8)

    float4 pA, pB;
    float leA, leB;

    // ---- reduction helpers ----
#define PSTAGE(MK) { \
    pA.x += __shfl_xor(pA.x, MK); pA.y += __shfl_xor(pA.y, MK); \
    pA.z += __shfl_xor(pA.z, MK); pA.w += __shfl_xor(pA.w, MK); \
    pB.x += __shfl_xor(pB.x, MK); pB.y += __shfl_xor(pB.y, MK); \
    pB.z += __shfl_xor(pB.z, MK); pB.w += __shfl_xor(pB.w, MK); }

#define PRED_WRITE() { \
    PSTAGE(4) PSTAGE(8) PSTAGE(16) PSTAGE(32) \
    if ((t & 63) < 4) { \
        ps[0][wave][ub+0] = pA.x; ps[0][wave][ub+1] = pA.y; \
        ps[0][wave][ub+2] = pA.z; ps[0][wave][ub+3] = pA.w; \
        ps[1][wave][ub+0] = pB.x; ps[1][wave][ub+1] = pB.y; \
        ps[1][wave][ub+2] = pB.z; ps[1][wave][ub+3] = pB.w; \
    } }

    // squash: threads 0..31 (wave 0). bi = batch, u = component.
#define SQUASH(USE_RED, WROUT) { \
    __syncthreads(); \
    if (t < 32) { \
        const int bi_ = t >> 4, u_ = t & 15; \
        float inv_; \
        if (USE_RED) { \
            float es_ = 0.f; \
            es_ += redB[bi_][0]; es_ += redB[bi_][1]; es_ += redB[bi_][2]; es_ += redB[bi_][3]; \
            es_ += redB[bi_][4]; es_ += redB[bi_][5]; es_ += redB[bi_][6]; es_ += redB[bi_][7]; \
            inv_ = 4.0f / es_;               /* 4x lane overcount in le */ \
        } else { \
            inv_ = 1.0f / 1152.0f;           /* softmax(ones) is uniform */ \
        } \
        float s_ = 0.f; \
        s_ += ps[bi_][0][u_]; s_ += ps[bi_][1][u_]; s_ += ps[bi_][2][u_]; s_ += ps[bi_][3][u_]; \
        s_ += ps[bi_][4][u_]; s_ += ps[bi_][5][u_]; s_ += ps[bi_][6][u_]; s_ += ps[bi_][7][u_]; \
        s_ *= inv_; \
        float sq_ = s_ * s_; \
        sq_ += __shfl_xor(sq_, 1); sq_ += __shfl_xor(sq_, 2); \
        sq_ += __shfl_xor(sq_, 4); sq_ += __shfl_xor(sq_, 8); \
        const float sc_ = sq_ / ((1.0f + sq_) * sqrtf(sq_ + 1e-9f)); \
        const float v_ = sc_ * s_; \
        v_s[bi_][u_] = v_; \
        if (WROUT) out[((size_t)(b0 + bi_) * CAPS + c) * UDIM + u_] = v_; \
    } \
    __syncthreads(); }

    // b update: butterfly over the 4 owner lanes; owner lane writes LDS.
#define BUP(K, UA, UB, INIT) { \
    float qa_ = UA.x*vA_.x + UA.y*vA_.y + UA.z*vA_.z + UA.w*vA_.w; \
    float qb_ = UB.x*vB_.x + UB.y*vB_.y + UB.z*vB_.z + UB.w*vB_.w; \
    qa_ += __shfl_xor(qa_, 1); qa_ += __shfl_xor(qa_, 2); \
    qb_ += __shfl_xor(qb_, 1); qb_ += __shfl_xor(qb_, 2); \
    if ((t & 3) == 0) { \
        const int n_ = gg + 128 * (K); \
        if (INIT) { b_s[0][n_] = 1.0f + qa_; b_s[1][n_] = 1.0f + qb_; } \
        else      { b_s[0][n_] += qa_;       b_s[1][n_] += qb_; } \
    } }

#define BUPD_ALL(INIT) { \
    const float4 vA_ = *(const float4*)(&v_s[0][ub]); \
    const float4 vB_ = *(const float4*)(&v_s[1][ub]); \
    BUP(0, uA0, uB0, INIT) BUP(1, uA1, uB1, INIT) \
    BUP(2, uA2, uB2, INIT) BUP(3, uA3, uB3, INIT) \
    BUP(4, uA4, uB4, INIT) BUP(5, uA5, uB5, INIT) \
    BUP(6, uA6, uB6, INIT) BUP(7, uA7, uB7, INIT) \
    BUP(8, uA8, uB8, INIT) \
    __syncthreads(); }

#define PADD(UA, UB) { \
    pA.x += UA.x; pA.y += UA.y; pA.z += UA.z; pA.w += UA.w; \
    pB.x += UB.x; pB.y += UB.y; pB.z += UB.z; pB.w += UB.w; }

#define ACCE(K, UA, UB) { \
    const float eA_ = expf(b_s[0][gg + 128*(K)]); \
    const float eB_ = expf(b_s[1][gg + 128*(K)]); \
    leA += eA_; leB += eB_; \
    pA.x += eA_*UA.x; pA.y += eA_*UA.y; pA.z += eA_*UA.z; pA.w += eA_*UA.w; \
    pB.x += eB_*UB.x; pB.y += eB_*UB.y; pB.z += eB_*UB.z; pB.w += eB_*UB.w; }

#define LERED_WRITE() { \
    leA += __shfl_xor(leA, 1);  leB += __shfl_xor(leB, 1); \
    leA += __shfl_xor(leA, 2);  leB += __shfl_xor(leB, 2); \
    leA += __shfl_xor(leA, 4);  leB += __shfl_xor(leB, 4); \
    leA += __shfl_xor(leA, 8);  leB += __shfl_xor(leB, 8); \
    leA += __shfl_xor(leA, 16); leB += __shfl_xor(leB, 16); \
    leA += __shfl_xor(leA, 32); leB += __shfl_xor(leB, 32); \
    if ((t & 63) == 0) { redB[0][wave] = leA; redB[1][wave] = leB; } }

    // ---- iteration 0: c is uniform 1/1152, no exp needed ----
    pA = uA0; pB = uB0;
    PADD(uA1, uB1) PADD(uA2, uB2) PADD(uA3, uB3) PADD(uA4, uB4)
    PADD(uA5, uB5) PADD(uA6, uB6) PADD(uA7, uB7) PADD(uA8, uB8)
    PRED_WRITE()
    SQUASH(0, 0)
    BUPD_ALL(1)            // b = 1 + u_hat . v0

    // ---- iteration 1 ----
    leA = 0.f; leB = 0.f;
    pA = make_float4(0.f, 0.f, 0.f, 0.f); pB = make_float4(0.f, 0.f, 0.f, 0.f);
    ACCE(0, uA0, uB0) ACCE(1, uA1, uB1) ACCE(2, uA2, uB2)
    ACCE(3, uA3, uB3) ACCE(4, uA4, uB4) ACCE(5, uA5, uB5)
    ACCE(6, uA6, uB6) ACCE(7, uA7, uB7) ACCE(8, uA8, uB8)
    LERED_WRITE()
    PRED_WRITE()
    SQUASH(1, 0)
    BUPD_ALL(0)            // b += u_hat . v1

    // ---- iteration 2 (writes out) ----
    leA = 0.f; leB = 0.f;
    pA = make_float4(0.f, 0.f, 0.f, 0.f); pB = make_float4(0.f, 0.f, 0.f, 0.f);
    ACCE(0, uA0, uB0) ACCE(1, uA1, uB1) ACCE(2, uA2, uB2)
    ACCE(3, uA3, uB3) ACCE(4, uA4, uB4) ACCE(5, uA5, uB5)
    ACCE(6, uA6, uB6) ACCE(7, uA7, uB7) ACCE(8, uA8, uB8)
    LERED_WRITE()
    PRED_WRITE()
    SQUASH(1, 1)
}

extern "C" void kernel_launch(void* const* d_in, const int* in_sizes, int n_in,
                              void* d_out, int out_size, void* d_ws, size_t ws_size,
                              hipStream_t stream) {
    const float* x = (const float*)d_in[0];   // (256, 1152, 8)
    const float* W = (const float*)d_in[1];   // (10, 1152, 8, 16)
    float* out = (float*)d_out;               // (256, 10, 16)
    capsule_routing_kernel<<<CAPS * (BATCH / 2), TPB, 0, stream>>>(x, W, out);
}